// Round 3
// baseline (1879.260 us; speedup 1.0000x reference)
//
#include <hip/hip_runtime.h>
#include <math.h>

#define QD 8192   // quant_dim (codebook size)
#define ED 512    // embed_dim
#define NT 8192   // n_tokens
#define KK 8      // top-k

typedef float fx4 __attribute__((ext_vector_type(4)));  // native vector: OK for nontemporal builtins

__device__ __forceinline__ float med3f(float a, float b, float c) {
  return __builtin_amdgcn_fmed3f(a, b, c);
}

// Sorted-descending top-8 insert: 8 cmp + 7 med3 + 1 max + 15 cndmask ≈ 31 VALU.
__device__ __forceinline__ void ins8(float val, int idx, float v[KK], int ix[KK]) {
  bool cgt[KK];
#pragma unroll
  for (int j = 0; j < KK; ++j) cgt[j] = val > v[j];
#pragma unroll
  for (int j = KK - 1; j >= 1; --j) {
    v[j]  = med3f(val, v[j - 1], v[j]);
    ix[j] = cgt[j] ? (cgt[j - 1] ? ix[j - 1] : idx) : ix[j];
  }
  v[0]  = fmaxf(v[0], val);
  ix[0] = cgt[0] ? idx : ix[0];
}

// weight [ED][QD] row-major  ->  wT [QD][ED] row-major
__global__ __launch_bounds__(256) void transpose_w(const float* __restrict__ w,
                                                   float* __restrict__ wT) {
  __shared__ float tile[32][33];  // +1 pad: no bank conflicts
  const int tx = threadIdx.x;     // 0..31
  const int ty = threadIdx.y;     // 0..7
  const int bx = blockIdx.x;      // quant tiles (QD/32 = 256)
  const int by = blockIdx.y;      // embed tiles (ED/32 = 16)
#pragma unroll
  for (int j = 0; j < 4; ++j) {
    const int r = by * 32 + ty + j * 8;  // embed row
    const int c = bx * 32 + tx;          // quant col
    tile[ty + j * 8][tx] = w[(size_t)r * QD + c];
  }
  __syncthreads();
#pragma unroll
  for (int j = 0; j < 4; ++j) {
    const int r = bx * 32 + ty + j * 8;  // quant row of wT
    const int c = by * 32 + tx;          // embed col
    wT[(size_t)r * ED + c] = tile[tx][ty + j * 8];
  }
}

// One wave (64 lanes) per token. 4 waves per block -> 4 tokens per block.
__global__ __launch_bounds__(256, 4) void topk_gather(const float* __restrict__ x,
                                                      const float* __restrict__ wsrc,
                                                      float* __restrict__ out,
                                                      int use_wt) {
  const int lane  = threadIdx.x & 63;
  const int wid   = threadIdx.x >> 6;
  const int token = blockIdx.x * 4 + wid;

  const fx4* __restrict__ xrow = (const fx4*)(x + (size_t)token * QD);

  // ---- Phase A: per-lane top-8 over 128 elements, 2-stage software pipeline ----
  // iteration it covers float4 indices [it*128, it*128+128): this lane takes
  // F0 = it*128 + lane and F1 = it*128 + 64 + lane (both wave-coalesced, 1 KB each).
  float v[KK];
  int   ix[KK];
#pragma unroll
  for (int j = 0; j < KK; ++j) { v[j] = -INFINITY; ix[j] = -1; }

  constexpr int ITER = QD / 4 / 128;  // 16
  fx4 c0 = __builtin_nontemporal_load(&xrow[lane]);
  fx4 c1 = __builtin_nontemporal_load(&xrow[64 + lane]);

#pragma unroll 2
  for (int it = 0; it < ITER; ++it) {
    const int nit = (it + 1 < ITER) ? (it + 1) : it;  // last iter: harmless reload
    fx4 n0 = __builtin_nontemporal_load(&xrow[nit * 128 + lane]);
    fx4 n1 = __builtin_nontemporal_load(&xrow[nit * 128 + 64 + lane]);

    const int b0 = (it * 128 + lane) * 4;
    const int b1 = (it * 128 + 64 + lane) * 4;
    ins8(c0.x, b0 + 0, v, ix);
    ins8(c0.y, b0 + 1, v, ix);
    ins8(c0.z, b0 + 2, v, ix);
    ins8(c0.w, b0 + 3, v, ix);
    ins8(c1.x, b1 + 0, v, ix);
    ins8(c1.y, b1 + 1, v, ix);
    ins8(c1.z, b1 + 2, v, ix);
    ins8(c1.w, b1 + 3, v, ix);

    c0 = n0;
    c1 = n1;
  }

  // ---- Phase B: merge 64 lane-lists -> wave top-8 via butterfly argmax ----
  // comparator: value desc, index asc (matches jax.lax.top_k tie-break)
  int widx[KK];
#pragma unroll
  for (int r = 0; r < KK; ++r) {
    float bv = v[0];
    int   bi = ix[0];
#pragma unroll
    for (int m = 32; m >= 1; m >>= 1) {
      const float ov = __shfl_xor(bv, m, 64);
      const int   oi = __shfl_xor(bi, m, 64);
      const bool take = (ov > bv) || (ov == bv && (unsigned)oi < (unsigned)bi);
      bv = take ? ov : bv;
      bi = take ? oi : bi;
    }
    widx[r] = bi;          // wave-uniform winner (global elem index, unique per row)
    if (bi == ix[0]) {     // only the origin lane matches (indices unique per token)
#pragma unroll
      for (int j = 0; j < KK - 1; ++j) { v[j] = v[j + 1]; ix[j] = ix[j + 1]; }
      v[KK - 1]  = -INFINITY;
      ix[KK - 1] = -1;
    }
  }

  // ---- Phase C: gather-and-sum 8 rows ----
  if (use_wt) {
    // wsrc = wT [QD][ED]: row widx[r] is 2KB contiguous (L2/L3-resident)
    fx4 acc0 = {0.f, 0.f, 0.f, 0.f};
    fx4 acc1 = {0.f, 0.f, 0.f, 0.f};
#pragma unroll
    for (int r = 0; r < KK; ++r) {
      const int row = __builtin_amdgcn_readfirstlane(widx[r]);  // uniform -> SGPR base
      const fx4* __restrict__ wrow = (const fx4*)(wsrc + (size_t)row * ED);
      const fx4 a = wrow[lane];
      const fx4 b = wrow[lane + 64];
      acc0 += a;
      acc1 += b;
    }
    fx4* __restrict__ orow = (fx4*)(out + (size_t)token * ED);
    __builtin_nontemporal_store(acc0, &orow[lane]);
    __builtin_nontemporal_store(acc1, &orow[lane + 64]);
  } else {
    // fallback: wsrc = weight [ED][QD] (uncoalesced column gather, correct but slow)
#pragma unroll
    for (int s = 0; s < ED / 64; ++s) {
      const int e = s * 64 + lane;
      float acc = 0.f;
#pragma unroll
      for (int r = 0; r < KK; ++r) {
        const int row = __builtin_amdgcn_readfirstlane(widx[r]);
        acc += wsrc[(size_t)e * QD + row];
      }
      out[(size_t)token * ED + e] = acc;
    }
  }
}

extern "C" void kernel_launch(void* const* d_in, const int* in_sizes, int n_in,
                              void* d_out, int out_size, void* d_ws, size_t ws_size,
                              hipStream_t stream) {
  const float* x = (const float*)d_in[0];   // [NT, QD] fp32
  const float* w = (const float*)d_in[1];   // [ED, QD] fp32
  float* out = (float*)d_out;               // [NT, ED] fp32
  float* wT  = (float*)d_ws;                // [QD, ED] fp32 scratch

  const size_t need = (size_t)QD * ED * sizeof(float);
  const int use_wt = (ws_size >= need) ? 1 : 0;

  if (use_wt) {
    dim3 tb(32, 8);
    dim3 tg(QD / 32, ED / 32);
    transpose_w<<<tg, tb, 0, stream>>>(w, wT);
  }
  topk_gather<<<NT / 4, 256, 0, stream>>>(x, use_wt ? wT : w, out, use_wt);
}

// Round 4
// 379.687 us; speedup vs baseline: 4.9495x; 4.9495x over previous
//
#include <hip/hip_runtime.h>
#include <math.h>

#define QD 8192   // quant_dim (codebook size)
#define ED 512    // embed_dim
#define NT 8192   // n_tokens
#define KK 8      // top-k

typedef float fx4 __attribute__((ext_vector_type(4)));  // native vector: OK for nontemporal builtins

__device__ __forceinline__ float med3f(float a, float b, float c) {
  return __builtin_amdgcn_fmed3f(a, b, c);
}

// weight [ED][QD] row-major  ->  wT [QD][ED] row-major
__global__ __launch_bounds__(256) void transpose_w(const float* __restrict__ w,
                                                   float* __restrict__ wT) {
  __shared__ float tile[32][33];  // +1 pad: no bank conflicts
  const int tx = threadIdx.x;     // 0..31
  const int ty = threadIdx.y;     // 0..7
  const int bx = blockIdx.x;      // quant tiles (QD/32 = 256)
  const int by = blockIdx.y;      // embed tiles (ED/32 = 16)
#pragma unroll
  for (int j = 0; j < 4; ++j) {
    const int r = by * 32 + ty + j * 8;  // embed row
    const int c = bx * 32 + tx;          // quant col
    tile[ty + j * 8][tx] = w[(size_t)r * QD + c];
  }
  __syncthreads();
#pragma unroll
  for (int j = 0; j < 4; ++j) {
    const int r = bx * 32 + ty + j * 8;  // quant row of wT
    const int c = by * 32 + tx;          // embed col
    wT[(size_t)r * ED + c] = tile[tx][ty + j * 8];
  }
}

// One wave (64 lanes) per token. 4 waves per block -> 4 tokens per block.
// NOTE (R3 lesson): the top-8 insert MUST stay inline in the loop body.
// Hoisting it into a function taking array params (float v[8]) defeats SROA ->
// AMDGPUPromoteAlloca demotes v[] to LDS (8192B/wg, 1.9e8 bank conflicts) and
// ix[] to scratch (5.6 GB HBM writes) -> 10x regression. Keep arrays local,
// indices compile-time constant, body inline.
__global__ __launch_bounds__(256, 4) void topk_gather(const float* __restrict__ x,
                                                      const float* __restrict__ wsrc,
                                                      float* __restrict__ out,
                                                      int use_wt) {
  const int lane  = threadIdx.x & 63;
  const int wid   = threadIdx.x >> 6;
  const int token = blockIdx.x * 4 + wid;

  const fx4* __restrict__ xrow = (const fx4*)(x + (size_t)token * QD);

  // ---- Phase A: per-lane top-8 (value desc; ties keep earlier index by strict >) ----
  float v[KK];
  int   ix[KK];
#pragma unroll
  for (int j = 0; j < KK; ++j) { v[j] = -INFINITY; ix[j] = -1; }

#pragma unroll 4
  for (int it = 0; it < QD / 4 / 64; ++it) {   // 32 iterations
    const int f4 = it * 64 + lane;             // coalesced: lane-contiguous float4s
    const fx4 q = __builtin_nontemporal_load(&xrow[f4]);  // stream-once: nt keeps wT L2-hot
    const int base = f4 * 4;
    const float e[4] = {q.x, q.y, q.z, q.w};
#pragma unroll
    for (int c = 0; c < 4; ++c) {
      const float val = e[c];
      const int   idx = base + c;
      bool cgt[KK];
#pragma unroll
      for (int j = 0; j < KK; ++j) cgt[j] = val > v[j];
      // shift-insert: med3(val, v[j-1], v[j]) == new value at slot j (list descending)
#pragma unroll
      for (int j = KK - 1; j >= 1; --j) {
        v[j]  = med3f(val, v[j - 1], v[j]);
        ix[j] = cgt[j] ? (cgt[j - 1] ? ix[j - 1] : idx) : ix[j];
      }
      v[0]  = fmaxf(v[0], val);
      ix[0] = cgt[0] ? idx : ix[0];
    }
  }

  // ---- Phase B: merge 64 lane-lists -> wave top-8 via butterfly argmax ----
  // comparator: value desc, index asc (matches jax.lax.top_k tie-break)
  int widx[KK];
#pragma unroll
  for (int r = 0; r < KK; ++r) {
    float bv = v[0];
    int   bi = ix[0];
#pragma unroll
    for (int m = 32; m >= 1; m >>= 1) {
      const float ov = __shfl_xor(bv, m, 64);
      const int   oi = __shfl_xor(bi, m, 64);
      const bool take = (ov > bv) || (ov == bv && (unsigned)oi < (unsigned)bi);
      bv = take ? ov : bv;
      bi = take ? oi : bi;
    }
    widx[r] = bi;          // wave-uniform winner (global elem index, unique per row)
    if (bi == ix[0]) {     // only the origin lane matches (indices unique per token)
#pragma unroll
      for (int j = 0; j < KK - 1; ++j) { v[j] = v[j + 1]; ix[j] = ix[j + 1]; }
      v[KK - 1]  = -INFINITY;
      ix[KK - 1] = -1;
    }
  }

  // ---- Phase C: gather-and-sum 8 rows ----
  if (use_wt) {
    // wsrc = wT [QD][ED]: row widx[r] is 2KB contiguous (L2/L3-resident)
    float4 acc0 = {0.f, 0.f, 0.f, 0.f};
    float4 acc1 = {0.f, 0.f, 0.f, 0.f};
#pragma unroll
    for (int r = 0; r < KK; ++r) {
      const int row = __builtin_amdgcn_readfirstlane(widx[r]);  // uniform -> SGPR base
      const float4* __restrict__ wrow = (const float4*)(wsrc + (size_t)row * ED);
      const float4 a = wrow[lane];
      const float4 b = wrow[lane + 64];
      acc0.x += a.x; acc0.y += a.y; acc0.z += a.z; acc0.w += a.w;
      acc1.x += b.x; acc1.y += b.y; acc1.z += b.z; acc1.w += b.w;
    }
    float4* __restrict__ orow = (float4*)(out + (size_t)token * ED);
    orow[lane]      = acc0;
    orow[lane + 64] = acc1;
  } else {
    // fallback: wsrc = weight [ED][QD] (uncoalesced column gather, correct but slow)
#pragma unroll
    for (int s = 0; s < ED / 64; ++s) {
      const int e = s * 64 + lane;
      float acc = 0.f;
#pragma unroll
      for (int r = 0; r < KK; ++r) {
        const int row = __builtin_amdgcn_readfirstlane(widx[r]);
        acc += wsrc[(size_t)e * QD + row];
      }
      out[(size_t)token * ED + e] = acc;
    }
  }
}

extern "C" void kernel_launch(void* const* d_in, const int* in_sizes, int n_in,
                              void* d_out, int out_size, void* d_ws, size_t ws_size,
                              hipStream_t stream) {
  const float* x = (const float*)d_in[0];   // [NT, QD] fp32
  const float* w = (const float*)d_in[1];   // [ED, QD] fp32
  float* out = (float*)d_out;               // [NT, ED] fp32
  float* wT  = (float*)d_ws;                // [QD, ED] fp32 scratch

  const size_t need = (size_t)QD * ED * sizeof(float);
  const int use_wt = (ws_size >= need) ? 1 : 0;

  if (use_wt) {
    dim3 tb(32, 8);
    dim3 tg(QD / 32, ED / 32);
    transpose_w<<<tg, tb, 0, stream>>>(w, wT);
  }
  topk_gather<<<NT / 4, 256, 0, stream>>>(x, use_wt ? wT : w, out, use_wt);
}